// Round 13
// baseline (2390.527 us; speedup 1.0000x reference)
//
#include <hip/hip_runtime.h>
#include <math.h>

#define Hdim 384
#define Wdim 384
#define HW (Hdim * Wdim)          // 147456
#define Bn 8
#define MAXITER 50
#define TOLF 1e-6f
#define EPSF 1e-12f

#define NPB 288                   // rr-partial width per image (k_init, K2)
#define NZ0 144                   // z0 (KtK) blocks per image: 12x12 tiles of 32x32
#define NZ1 288                   // z1 (LtL) blocks per image: 24x12 tiles of 16x32

// z0 LDS geometry (32x32 tile, halo 6 / t1 halo 4) — odd strides = natural bank swizzle
#define DSH 44
#define DSW 44
#define DSP 45
#define Z0SLOTS 1936
#define T1H 40
#define T1W 40
#define T1P 41

#define KSL 2916                  // 9 planes * 18 rows * 18 h2-cols

typedef _Float16 h2 __attribute__((ext_vector_type(2)));

struct Z0S { float ds[DSH][DSP]; float t1s[T1H][T1P]; };              // 14480 B
struct Z1S { _Float16 kern[9][18][36]; float dsm[20][37]; float u2[18][36]; }; // 17216 B
union SMemU { Z0S z0; Z1S z1; };

// ---------- helpers ----------

__device__ __forceinline__ int symidx(int t, int n) {
    if (t < 0) t = -t - 1;
    else if (t >= n) t = 2 * n - 1 - t;
    return t;
}

__device__ __forceinline__ float blockReduceSum256(float v) {
    __shared__ float sm[256];
    sm[threadIdx.x] = v;
    __syncthreads();
    for (int s = 128; s > 0; s >>= 1) {
        if (threadIdx.x < s) sm[threadIdx.x] += sm[threadIdx.x + s];
        __syncthreads();
    }
    float r = sm[0];
    __syncthreads();
    return r;
}

// wave-shuffle block sum: identical fixed order in every block (validated r8-r10)
__device__ __forceinline__ float blockSum(float v, float* red4) {
#pragma unroll
    for (int o = 32; o > 0; o >>= 1) v += __shfl_down(v, o, 64);
    int lane = threadIdx.x & 63, wid = threadIdx.x >> 6;
    if (lane == 0) red4[wid] = v;
    __syncthreads();
    float s = (red4[0] + red4[1]) + (red4[2] + red4[3]);
    __syncthreads();
    return s;
}

// global-memory sym_conv_T (k_init only; proven rounds 1-12)
__device__ float symconvT_s(const float* __restrict__ g, const float* kr, int m, int n) {
    int pr[2]; int nr = 0;
    pr[nr++] = m + 2;
    if (m < 2)         pr[nr++] = 1 - m;
    if (m >= Hdim - 2) pr[nr++] = 2 * Hdim + 1 - m;
    int pc[2]; int nc = 0;
    pc[nc++] = n + 2;
    if (n < 2)         pc[nc++] = 1 - n;
    if (n >= Wdim - 2) pc[nc++] = 2 * Wdim + 1 - n;

    float acc = 0.f;
    for (int a = 0; a < nr; ++a) {
        int p = pr[a];
        for (int bb = 0; bb < nc; ++bb) {
            int q = pc[bb];
#pragma unroll
            for (int u = 0; u < 5; ++u) {
                int rr = p + u - 4;
                if ((unsigned)rr < (unsigned)Hdim) {
                    const float* row = g + rr * Wdim;
#pragma unroll
                    for (int v = 0; v < 5; ++v) {
                        int cc = q + v - 4;
                        if ((unsigned)cc < (unsigned)Wdim)
                            acc += kr[u * 5 + v] * row[cc];
                    }
                }
            }
        }
    }
    return acc;
}

// r = b = K^T y ; x = 0 ; partials of b*b
__global__ __launch_bounds__(256) void k_init(const float* __restrict__ y, const float* __restrict__ kk,
                                              float* __restrict__ r, float* __restrict__ x,
                                              float* __restrict__ part) {
    __shared__ float krs[25];
    int b = blockIdx.y;
    if (threadIdx.x < 25) krs[threadIdx.x] = kk[b * 25 + threadIdx.x];
    __syncthreads();
    int p2 = (blockIdx.x * 256 + threadIdx.x) * 2;
    int m = p2 / Wdim, n = p2 - m * Wdim;
    const float* gb = y + (size_t)b * HW;
    float a0 = symconvT_s(gb, krs, m, n);
    float a1 = symconvT_s(gb, krs, m, n + 1);
    size_t off = (size_t)b * HW + p2;
    r[off] = a0; r[off + 1] = a1;
    x[off] = 0.f; x[off + 1] = 0.f;
    float ps = blockReduceSum256(a0 * a0 + a1 * a1);
    if (threadIdx.x == 0) part[b * NPB + blockIdx.x] = ps;
}

// kern = fp16( f * (1/max(sum|f|,eps)) )
__global__ __launch_bounds__(256) void k_prep(const float* __restrict__ f, _Float16* __restrict__ kh) {
    int id = blockIdx.x;
    int b = id & 7;
    int base = (id >> 3) * 512 + threadIdx.x * 2;
    const float* fb = f + (size_t)b * 9 * HW;
    _Float16* khb = kh + (size_t)b * 9 * HW;
    float v0[9], v1[9];
    float s0 = 0.f, s1 = 0.f;
#pragma unroll
    for (int c = 0; c < 9; ++c) {
        float2 fv = *(const float2*)(fb + (size_t)c * HW + base);
        v0[c] = fv.x; v1[c] = fv.y;
        s0 += fabsf(fv.x); s1 += fabsf(fv.y);
    }
    float r0 = 1.f / fmaxf(s0, EPSF);
    float r1 = 1.f / fmaxf(s1, EPSF);
#pragma unroll
    for (int c = 0; c < 9; ++c) {
        khb[(size_t)c * HW + base]     = (_Float16)(v0[c] * r0);
        khb[(size_t)c * HW + base + 1] = (_Float16)(v1[c] * r1);
    }
}

// ---------- K1: role-split (z0: beta/d-build + K^TK ; z1: L^TL gather) ----------
// Dispatch interleave: per image, block sequence [z0, z1, z1] repeating — mixes
// heavy/light roles on each CU while preserving b = id&7 XCD pinning.

template <int KH>
__global__ __launch_bounds__(256, 4) void K1(
    const float* __restrict__ r, const float* __restrict__ dold, float* __restrict__ dnew,
    float* __restrict__ qa, _Float16* __restrict__ qb,
    const float* __restrict__ f, const _Float16* __restrict__ kern,
    const float* __restrict__ kk,
    const float* __restrict__ rrp, float* __restrict__ dqa, float* __restrict__ dqb,
    const float* __restrict__ deltaO, float* __restrict__ deltaN,
    const int* __restrict__ convO, int* __restrict__ convN,
    float* __restrict__ thrS, int isFirst)
{
    __shared__ SMemU sm;
    __shared__ float red4[4];
    __shared__ float krs[25];

    int id = blockIdx.x;
    int b = id & 7;
    int g8 = id >> 3;                 // 0..431 per image
    int zi = g8 % 3;                  // 0 -> z0 ; 1,2 -> z1
    int t3 = g8 / 3;                  // 0..143
    bool roleK = (zi == 0);
    int bxg = roleK ? t3 : (t3 * 2 + (zi - 1));   // z0: 0..143 ; z1: 0..287
    int tid = threadIdx.x;
    size_t bHW = (size_t)b * HW;
    const float* rb = r + bHW;
    const float* db = dold + bHW;

    // ---- preload (all independent loads issued before the beta reduce) ----
    float rv0[8], dv0[8];
    float rv1[3], dv1[3];
    h2 kv[12];
    int r0, c0;
    if (roleK) {
        int ty = bxg / 12, tx = bxg - ty * 12;
        r0 = ty * 32; c0 = tx * 32;
        if (tid < 25) krs[tid] = kk[b * 25 + tid];
#pragma unroll
        for (int p = 0; p < 8; ++p) {
            int e = p * 256 + tid;
            int a = e / DSW, ee = e - a * DSW;
            int gr = r0 - 6 + a, gc = c0 - 6 + ee;
            bool v = (e < Z0SLOTS) && ((unsigned)gr < (unsigned)Hdim) && ((unsigned)gc < (unsigned)Wdim);
            size_t gg = (size_t)gr * Wdim + gc;
            rv0[p] = v ? rb[gg] : 0.f;
            dv0[p] = (v && !isFirst) ? db[gg] : 0.f;
        }
    } else {
        int ty = bxg / 12, tx = bxg - ty * 12;
        r0 = ty * 16; c0 = tx * 32;
        if (KH) {
            // fixed-unroll kern preload: 12 independent predicated h2 loads
            const _Float16* khb = kern + (size_t)b * 9 * HW;
#pragma unroll
            for (int p = 0; p < 12; ++p) {
                int e = p * 256 + tid;
                h2 hv; hv[0] = (_Float16)0.f; hv[1] = (_Float16)0.f;
                if (e < KSL) {
                    int cpl = e / 324;
                    int s2 = e - cpl * 324;
                    int sa = s2 / 18, j = s2 - sa * 18;
                    int gr = r0 - 1 + sa, gc = c0 - 2 + 2 * j;
                    if ((unsigned)gr < (unsigned)Hdim) {
                        const _Float16* rowp = khb + (size_t)cpl * HW + (size_t)gr * Wdim;
                        if (gc >= 0 && gc + 1 < Wdim) hv = *(const h2*)(rowp + gc);
                        else {
                            if ((unsigned)gc < (unsigned)Wdim) hv[0] = rowp[gc];
                            if ((unsigned)(gc + 1) < (unsigned)Wdim) hv[1] = rowp[gc + 1];
                        }
                    }
                }
                kv[p] = hv;
            }
        }
        // r/d halo-2 regs (20x36 = 720 slots)
#pragma unroll
        for (int p = 0; p < 3; ++p) {
            int e = p * 256 + tid;
            int a = e / 36, ee = e - a * 36;
            int gr = r0 - 2 + a, gc = c0 - 2 + ee;
            bool v = (e < 720) && ((unsigned)gr < (unsigned)Hdim) && ((unsigned)gc < (unsigned)Wdim);
            size_t gg = (size_t)gr * Wdim + gc;
            rv1[p] = v ? rb[gg] : 0.f;
            dv1[p] = (v && !isFirst) ? db[gg] : 0.f;
        }
        if (!KH) {
            // fallback: fp32 f load + on-the-fly normalize (unused when ws fits)
            const float* fb = f + (size_t)b * 9 * HW;
            for (int e = tid; e < 18 * 36; e += 256) {
                int sa = e / 36, se = e - sa * 36;
                int gr = r0 - 1 + sa, gc = c0 - 2 + se;
                bool v = ((unsigned)gr < (unsigned)Hdim) && ((unsigned)gc < (unsigned)Wdim);
                size_t gg = (size_t)gr * Wdim + gc;
                float fv[9]; float sab = 0.f;
#pragma unroll
                for (int c = 0; c < 9; ++c) {
                    fv[c] = v ? fb[(size_t)c * HW + gg] : 0.f;
                    sab += fabsf(fv[c]);
                }
                float rd = 1.f / fmaxf(sab, EPSF);
#pragma unroll
                for (int c = 0; c < 9; ++c)
                    sm.z1.kern[c][sa][se] = (_Float16)(fv[c] * rd);
            }
        }
    }

    // ---- beta reduce (identical order in every block) ----
    float s0r = rrp[b * NPB + tid] + ((tid < 32) ? rrp[b * NPB + 256 + tid] : 0.f);
    float delta = blockSum(s0r, red4);
    float beta = isFirst ? 0.f : delta / deltaO[b];
    if (g8 == 0 && tid == 0) {
        deltaN[b] = delta;
        if (isFirst) {
            float th = TOLF * delta;
            thrS[b] = th;
            convN[b] = (delta <= th) ? 1 : 0;
        } else {
            convN[b] = (convO[b] || delta <= thrS[b]) ? 1 : 0;
        }
    }

    if (roleK) {
        // ---- z0: ds = d_new over tile+halo6 ----
#pragma unroll
        for (int p = 0; p < 8; ++p) {
            int e = p * 256 + tid;
            if (e < Z0SLOTS) {
                int a = e / DSW, ee = e - a * DSW;
                sm.z0.ds[a][ee] = isFirst ? rv0[p] : rv0[p] + beta * dv0[p];
            }
        }
        __syncthreads();

        int trr = tid >> 3, tcc = (tid & 7) << 2;
        size_t ooff = bHW + (size_t)(r0 + trr) * Wdim + c0 + tcc;
        float4 dn4 = make_float4(sm.z0.ds[trr + 6][tcc + 6], sm.z0.ds[trr + 6][tcc + 7],
                                 sm.z0.ds[trr + 6][tcc + 8], sm.z0.ds[trr + 6][tcc + 9]);
        *(float4*)(dnew + ooff) = dn4;

        bool interior = (r0 >= 32 && r0 <= 320 && c0 >= 32 && c0 <= 320);

        // ---- t1 = sym_conv(d) over tile+halo4 ----
        if (interior) {
            for (int e = tid; e < 400; e += 256) {
                int lr = e / 10, lc4 = (e - lr * 10) * 4;
                float a0 = 0, a1 = 0, a2 = 0, a3 = 0;
#pragma unroll
                for (int u = 0; u < 5; ++u) {
                    const float* drow = &sm.z0.ds[lr + 4 - u][lc4];
                    float w[8];
#pragma unroll
                    for (int z = 0; z < 8; ++z) w[z] = drow[z];
#pragma unroll
                    for (int v = 0; v < 5; ++v) {
                        float kv2 = krs[u * 5 + v];
                        a0 += kv2 * w[4 - v]; a1 += kv2 * w[5 - v];
                        a2 += kv2 * w[6 - v]; a3 += kv2 * w[7 - v];
                    }
                }
                sm.z0.t1s[lr][lc4] = a0; sm.z0.t1s[lr][lc4 + 1] = a1;
                sm.z0.t1s[lr][lc4 + 2] = a2; sm.z0.t1s[lr][lc4 + 3] = a3;
            }
        } else {
            for (int e = tid; e < T1H * T1W; e += 256) {
                int lr = e / T1W, lc = e - lr * T1W;
                int gi = r0 - 4 + lr, gj = c0 - 4 + lc;
                float v = 0.f;
                if ((unsigned)gi < (unsigned)Hdim && (unsigned)gj < (unsigned)Wdim) {
                    float acc = 0.f;
#pragma unroll
                    for (int u = 0; u < 5; ++u) {
                        int rr = symidx(gi + 2 - u, Hdim) - (r0 - 6);
#pragma unroll
                        for (int vv = 0; vv < 5; ++vv) {
                            int cc = symidx(gj + 2 - vv, Wdim) - (c0 - 6);
                            acc += krs[u * 5 + vv] * sm.z0.ds[rr][cc];
                        }
                    }
                    v = acc;
                }
                sm.z0.t1s[lr][lc] = v;
            }
        }
        __syncthreads();

        // ---- qa = sym_conv_T(t1) ; dq_a partial ----
        int m = r0 + trr, n = c0 + tcc;
        float q0, q1, q2, q3;
        if (interior) {
            float a0 = 0, a1 = 0, a2 = 0, a3 = 0;
#pragma unroll
            for (int u = 0; u < 5; ++u) {
                const float* t1row = &sm.z0.t1s[trr + 2 + u][tcc + 2];
                float w[8];
#pragma unroll
                for (int z = 0; z < 8; ++z) w[z] = t1row[z];
#pragma unroll
                for (int v = 0; v < 5; ++v) {
                    float kv2 = krs[u * 5 + v];
                    a0 += kv2 * w[v]; a1 += kv2 * w[v + 1];
                    a2 += kv2 * w[v + 2]; a3 += kv2 * w[v + 3];
                }
            }
            q0 = a0; q1 = a1; q2 = a2; q3 = a3;
        } else {
            float qo[4];
#pragma unroll
            for (int o = 0; o < 4; ++o) {
                int nn = n + o;
                int pr[2]; int nr = 0;
                pr[nr++] = m + 2;
                if (m < 2)         pr[nr++] = 1 - m;
                if (m >= Hdim - 2) pr[nr++] = 2 * Hdim + 1 - m;
                int pc[2]; int nc = 0;
                pc[nc++] = nn + 2;
                if (nn < 2)         pc[nc++] = 1 - nn;
                if (nn >= Wdim - 2) pc[nc++] = 2 * Wdim + 1 - nn;
                float acc = 0.f;
                for (int a = 0; a < nr; ++a) {
                    int p = pr[a];
                    for (int bb = 0; bb < nc; ++bb) {
                        int qq2 = pc[bb];
#pragma unroll
                        for (int u = 0; u < 5; ++u) {
                            int rr = p + u - 4;
                            if ((unsigned)rr < (unsigned)Hdim) {
                                int lrr = rr - (r0 - 4);
#pragma unroll
                                for (int v = 0; v < 5; ++v) {
                                    int cc = qq2 + v - 4;
                                    if ((unsigned)cc < (unsigned)Wdim)
                                        acc += krs[u * 5 + v] * sm.z0.t1s[lrr][cc - (c0 - 4)];
                                }
                            }
                        }
                    }
                }
                qo[o] = acc;
            }
            q0 = qo[0]; q1 = qo[1]; q2 = qo[2]; q3 = qo[3];
        }
        *(float4*)(qa + ooff) = make_float4(q0, q1, q2, q3);

        float pdq = dn4.x * q0 + dn4.y * q1 + dn4.z * q2 + dn4.w * q3;
        float dq = blockSum(pdq, red4);
        if (tid == 0) dqa[b * NZ0 + bxg] = dq;

    } else {
        // ---- kern LDS fill from preloaded regs + dsm = d_new over tile+halo2 ----
        if (KH) {
#pragma unroll
            for (int p = 0; p < 12; ++p) {
                int e = p * 256 + tid;
                if (e < KSL) {
                    int cpl = e / 324;
                    int s2 = e - cpl * 324;
                    int sa = s2 / 18, j = s2 - sa * 18;
                    *(h2*)&sm.z1.kern[cpl][sa][2 * j] = kv[p];
                }
            }
        }
#pragma unroll
        for (int p = 0; p < 3; ++p) {
            int e = p * 256 + tid;
            if (e < 720) {
                int a = e / 36, ee = e - a * 36;
                sm.z1.dsm[a][ee] = isFirst ? rv1[p] : rv1[p] + beta * dv1[p];
            }
        }
        __syncthreads();

        // ---- u2[s] = sum_c kern[c,s] * d(s+delta_c)  over 18x34 (se 1..34) ----
        for (int e = tid; e < 612; e += 256) {
            int sa = e / 34, se = 1 + (e - sa * 34);
            float acc = 0.f;
#pragma unroll
            for (int c = 0; c < 9; ++c)
                acc += (float)sm.z1.kern[c][sa][se] * sm.z1.dsm[sa + c / 3][se - 1 + c % 3];
            sm.z1.u2[sa][se] = acc;
        }
        __syncthreads();

        // ---- gather: qb(p) = sum_c kern[c, p-dc] * u2(p-dc) ; dq_b partial ----
        int ti = tid >> 4, tj0 = (tid & 15) << 1;
        h2 qh;
        float pdq = 0.f;
#pragma unroll
        for (int oo = 0; oo < 2; ++oo) {
            int tj = tj0 + oo;
            float qv = 0.f;
#pragma unroll
            for (int c = 0; c < 9; ++c) {
                int sa = ti + 2 - c / 3, se = tj + 3 - c % 3;
                qv += (float)sm.z1.kern[c][sa][se] * sm.z1.u2[sa][se];
            }
            qh[oo] = (_Float16)qv;
            pdq += sm.z1.dsm[ti + 2][tj + 2] * (float)qh[oo];
        }
        *(h2*)(qb + bHW + (size_t)(r0 + ti) * Wdim + c0 + tj0) = qh;
        float dq = blockSum(pdq, red4);
        if (tid == 0) dqb[b * NZ1 + bxg] = dq;
    }
}

// ---------- K2: alpha ; q=qa+lam*qb ; x += a d ; r -= a q ; rr partials ----------

__global__ __launch_bounds__(256) void K2(
    const float* __restrict__ dqa, const float* __restrict__ dqb, const float* __restrict__ rw,
    const float* __restrict__ deltaN, const int* __restrict__ convN,
    const float* __restrict__ d, const float* __restrict__ qa, const _Float16* __restrict__ qb,
    float* __restrict__ x, float* __restrict__ r, float* __restrict__ rrp)
{
    __shared__ float red[512];
    int id = blockIdx.x;
    int b = id & 7, bx = id >> 3, tid = threadIdx.x;
    float sA = (tid < NZ0) ? dqa[b * NZ0 + tid] : 0.f;
    float sB = dqb[b * NZ1 + tid] + ((tid < 32) ? dqb[b * NZ1 + 256 + tid] : 0.f);
    red[tid] = sA; red[256 + tid] = sB;
    __syncthreads();
    for (int st = 128; st > 0; st >>= 1) {
        if (tid < st) { red[tid] += red[tid + st]; red[256 + tid] += red[256 + tid + st]; }
        __syncthreads();
    }
    float lam = expf(rw[0]);
    float dq = red[0] + lam * red[256];
    float a = convN[b] ? 0.f : deltaN[b] / dq;
    __syncthreads();

    size_t off = (size_t)b * HW + ((size_t)bx * 256 + tid) * 2;
    float2 d2  = *(const float2*)(d + off);
    float2 qa2 = *(const float2*)(qa + off);
    h2 qh = *(const h2*)(qb + off);
    float2 xv  = *(float2*)(x + off);
    float2 rv  = *(float2*)(r + off);
    float q0 = qa2.x + lam * (float)qh[0], q1 = qa2.y + lam * (float)qh[1];
    xv.x += a * d2.x; xv.y += a * d2.y;
    rv.x -= a * q0;   rv.y -= a * q1;
    *(float2*)(x + off) = xv;
    *(float2*)(r + off) = rv;

    float ps = rv.x * rv.x + rv.y * rv.y;
    red[tid] = ps; __syncthreads();
    for (int st = 128; st > 0; st >>= 1) {
        if (tid < st) red[tid] += red[tid + st];
        __syncthreads();
    }
    if (tid == 0) rrp[b * NPB + bx] = red[0];
}

// ---------- launch ----------

extern "C" void kernel_launch(void* const* d_in, const int* in_sizes, int n_in,
                              void* d_out, int out_size, void* d_ws, size_t ws_size,
                              hipStream_t stream) {
    const float* y  = (const float*)d_in[0];   // [8,1,384,384]
    const float* kk = (const float*)d_in[1];   // [8,5,5]
    const float* f  = (const float*)d_in[2];   // [8,9,384,384]
    const float* rw = (const float*)d_in[3];   // [1]

    float* x = (float*)d_out;
    float* ws = (float*)d_ws;
    const size_t N = (size_t)Bn * HW;

    float* r    = ws;
    float* d0   = ws + 1 * N;
    float* d1   = ws + 2 * N;
    float* qa   = ws + 3 * N;
    float* qbF  = ws + 4 * N;          // fp16 qb lives in this N-float region
    float* P    = ws + 5 * N;
    float* dqa  = P;                   P += (size_t)Bn * NZ0;
    float* dqb  = P;                   P += (size_t)Bn * NZ1;
    float* rrp  = P;                   P += (size_t)Bn * NPB;
    float* delta = P;                  P += 2 * Bn;
    float* thr   = P;                  P += Bn;
    int*   conv  = (int*)P;            P += 2 * Bn;
    _Float16* kern = (_Float16*)P;     // 9N halves
    _Float16* qb = (_Float16*)qbF;
    size_t needBytes = ((size_t)(P - ws)) * 4 + 9 * N * 2;
    int useH = (ws_size >= needBytes) ? 1 : 0;
    float* db[2] = { d0, d1 };

    dim3 blk(256);

    k_init<<<dim3(NPB, Bn), blk, 0, stream>>>(y, kk, r, x, rrp);
    if (useH) k_prep<<<dim3(NPB * Bn), blk, 0, stream>>>(f, kern);

    for (int t = 0; t < MAXITER; ++t) {
        int i = t & 1, o = i ^ 1;
        if (useH) {
            K1<1><<<dim3((NZ0 + NZ1) * Bn), blk, 0, stream>>>(
                r, db[i], db[o], qa, qb, f, kern, kk,
                rrp, dqa, dqb,
                delta + i * Bn, delta + o * Bn,
                conv + i * Bn, conv + o * Bn,
                thr, t == 0 ? 1 : 0);
        } else {
            K1<0><<<dim3((NZ0 + NZ1) * Bn), blk, 0, stream>>>(
                r, db[i], db[o], qa, qb, f, kern, kk,
                rrp, dqa, dqb,
                delta + i * Bn, delta + o * Bn,
                conv + i * Bn, conv + o * Bn,
                thr, t == 0 ? 1 : 0);
        }
        K2<<<dim3(NPB * Bn), blk, 0, stream>>>(
            dqa, dqb, rw, delta + o * Bn, conv + o * Bn,
            db[o], qa, qb, x, r, rrp);
    }
}

// Round 14
// 1868.845 us; speedup vs baseline: 1.2791x; 1.2791x over previous
//
#include <hip/hip_runtime.h>
#include <math.h>

#define Hdim 384
#define Wdim 384
#define HW (Hdim * Wdim)          // 147456
#define Bn 8
#define MAXITER 50
#define TOLF 1e-6f
#define EPSF 1e-12f

#define NPB 288                   // rr-partial width per image (k_init, K2)
#define NZ0 144                   // z0 (KtK) blocks per image: 12x12 tiles of 32x32
#define NZ1 288                   // z1 (LtL) blocks per image: 24x12 tiles of 16x32

// z0 LDS geometry (32x32 tile, halo 6 / t1 halo 4) — odd strides = natural bank swizzle
#define DSH 44
#define DSW 44
#define DSP 45
#define Z0SLOTS 1936
#define T1H 40
#define T1W 40
#define T1P 41

#define KSL 2916                  // 9 planes * 18 rows * 18 h2-cols

typedef _Float16 h2 __attribute__((ext_vector_type(2)));

struct Z0S { float ds[DSH][DSP]; float t1s[T1H][T1P]; };              // 14480 B
struct Z1S { _Float16 kern[9][18][36]; float dsm[20][37]; float u2[18][36]; }; // 17216 B
union SMemU { Z0S z0; Z1S z1; };

// ---------- helpers ----------

__device__ __forceinline__ int symidx(int t, int n) {
    if (t < 0) t = -t - 1;
    else if (t >= n) t = 2 * n - 1 - t;
    return t;
}

__device__ __forceinline__ float blockReduceSum256(float v) {
    __shared__ float sm[256];
    sm[threadIdx.x] = v;
    __syncthreads();
    for (int s = 128; s > 0; s >>= 1) {
        if (threadIdx.x < s) sm[threadIdx.x] += sm[threadIdx.x + s];
        __syncthreads();
    }
    float r = sm[0];
    __syncthreads();
    return r;
}

// wave-shuffle block sum: identical fixed order in every block (validated r8-r10)
__device__ __forceinline__ float blockSum(float v, float* red4) {
#pragma unroll
    for (int o = 32; o > 0; o >>= 1) v += __shfl_down(v, o, 64);
    int lane = threadIdx.x & 63, wid = threadIdx.x >> 6;
    if (lane == 0) red4[wid] = v;
    __syncthreads();
    float s = (red4[0] + red4[1]) + (red4[2] + red4[3]);
    __syncthreads();
    return s;
}

// global-memory sym_conv_T (k_init only; proven rounds 1-10)
__device__ float symconvT_s(const float* __restrict__ g, const float* kr, int m, int n) {
    int pr[2]; int nr = 0;
    pr[nr++] = m + 2;
    if (m < 2)         pr[nr++] = 1 - m;
    if (m >= Hdim - 2) pr[nr++] = 2 * Hdim + 1 - m;
    int pc[2]; int nc = 0;
    pc[nc++] = n + 2;
    if (n < 2)         pc[nc++] = 1 - n;
    if (n >= Wdim - 2) pc[nc++] = 2 * Wdim + 1 - n;

    float acc = 0.f;
    for (int a = 0; a < nr; ++a) {
        int p = pr[a];
        for (int bb = 0; bb < nc; ++bb) {
            int q = pc[bb];
#pragma unroll
            for (int u = 0; u < 5; ++u) {
                int rr = p + u - 4;
                if ((unsigned)rr < (unsigned)Hdim) {
                    const float* row = g + rr * Wdim;
#pragma unroll
                    for (int v = 0; v < 5; ++v) {
                        int cc = q + v - 4;
                        if ((unsigned)cc < (unsigned)Wdim)
                            acc += kr[u * 5 + v] * row[cc];
                    }
                }
            }
        }
    }
    return acc;
}

// r = b = K^T y ; x = 0 ; partials of b*b
__global__ __launch_bounds__(256) void k_init(const float* __restrict__ y, const float* __restrict__ kk,
                                              float* __restrict__ r, float* __restrict__ x,
                                              float* __restrict__ part) {
    __shared__ float krs[25];
    int b = blockIdx.y;
    if (threadIdx.x < 25) krs[threadIdx.x] = kk[b * 25 + threadIdx.x];
    __syncthreads();
    int p2 = (blockIdx.x * 256 + threadIdx.x) * 2;
    int m = p2 / Wdim, n = p2 - m * Wdim;
    const float* gb = y + (size_t)b * HW;
    float a0 = symconvT_s(gb, krs, m, n);
    float a1 = symconvT_s(gb, krs, m, n + 1);
    size_t off = (size_t)b * HW + p2;
    r[off] = a0; r[off + 1] = a1;
    x[off] = 0.f; x[off + 1] = 0.f;
    float ps = blockReduceSum256(a0 * a0 + a1 * a1);
    if (threadIdx.x == 0) part[b * NPB + blockIdx.x] = ps;
}

// kern = fp16( f * (1/max(sum|f|,eps)) )
__global__ __launch_bounds__(256) void k_prep(const float* __restrict__ f, _Float16* __restrict__ kh) {
    int id = blockIdx.x;
    int b = id & 7;
    int base = (id >> 3) * 512 + threadIdx.x * 2;
    const float* fb = f + (size_t)b * 9 * HW;
    _Float16* khb = kh + (size_t)b * 9 * HW;
    float v0[9], v1[9];
    float s0 = 0.f, s1 = 0.f;
#pragma unroll
    for (int c = 0; c < 9; ++c) {
        float2 fv = *(const float2*)(fb + (size_t)c * HW + base);
        v0[c] = fv.x; v1[c] = fv.y;
        s0 += fabsf(fv.x); s1 += fabsf(fv.y);
    }
    float r0 = 1.f / fmaxf(s0, EPSF);
    float r1 = 1.f / fmaxf(s1, EPSF);
#pragma unroll
    for (int c = 0; c < 9; ++c) {
        khb[(size_t)c * HW + base]     = (_Float16)(v0[c] * r0);
        khb[(size_t)c * HW + base + 1] = (_Float16)(v1[c] * r1);
    }
}

// ---------- K1: role-split (z0: beta/d-build + K^TK ; z1: L^TL gather) ----------

template <int KH>
__global__ __launch_bounds__(256, 4) void K1(
    const float* __restrict__ r, const float* __restrict__ dold, float* __restrict__ dnew,
    float* __restrict__ qa, _Float16* __restrict__ qb,
    const float* __restrict__ f, const _Float16* __restrict__ kern,
    const float* __restrict__ kk,
    const float* __restrict__ rrp, float* __restrict__ dqa, float* __restrict__ dqb,
    const float* __restrict__ deltaO, float* __restrict__ deltaN,
    const int* __restrict__ convO, int* __restrict__ convN,
    float* __restrict__ thrS, int isFirst)
{
    __shared__ SMemU sm;
    __shared__ float red4[4];
    __shared__ float krs[25];

    int id = blockIdx.x;
    int b = id & 7;
    int bxg = id >> 3;
    int tid = threadIdx.x;
    bool roleK = (bxg < NZ0);
    size_t bHW = (size_t)b * HW;
    const float* rb = r + bHW;
    const float* db = dold + bHW;

    // ---- preload (all independent loads issued before the beta reduce) ----
    float rv0[8], dv0[8];
    float rv1[3], dv1[3];
    h2 kv[12];
    int r0, c0;
    if (roleK) {
        int ty = bxg / 12, tx = bxg - ty * 12;
        r0 = ty * 32; c0 = tx * 32;
        if (tid < 25) krs[tid] = kk[b * 25 + tid];
#pragma unroll
        for (int p = 0; p < 8; ++p) {
            int e = p * 256 + tid;
            int a = e / DSW, ee = e - a * DSW;
            int gr = r0 - 6 + a, gc = c0 - 6 + ee;
            bool v = (e < Z0SLOTS) && ((unsigned)gr < (unsigned)Hdim) && ((unsigned)gc < (unsigned)Wdim);
            size_t gg = (size_t)gr * Wdim + gc;
            rv0[p] = v ? rb[gg] : 0.f;
            dv0[p] = (v && !isFirst) ? db[gg] : 0.f;
        }
    } else {
        int bxl = bxg - NZ0;
        int ty = bxl / 12, tx = bxl - ty * 12;
        r0 = ty * 16; c0 = tx * 32;
        if (KH) {
            // fixed-unroll kern preload: 12 independent predicated h2 loads
            const _Float16* khb = kern + (size_t)b * 9 * HW;
#pragma unroll
            for (int p = 0; p < 12; ++p) {
                int e = p * 256 + tid;
                h2 hv; hv[0] = (_Float16)0.f; hv[1] = (_Float16)0.f;
                if (e < KSL) {
                    int cpl = e / 324;
                    int s2 = e - cpl * 324;
                    int sa = s2 / 18, j = s2 - sa * 18;
                    int gr = r0 - 1 + sa, gc = c0 - 2 + 2 * j;
                    if ((unsigned)gr < (unsigned)Hdim) {
                        const _Float16* rowp = khb + (size_t)cpl * HW + (size_t)gr * Wdim;
                        if (gc >= 0 && gc + 1 < Wdim) hv = *(const h2*)(rowp + gc);
                        else {
                            if ((unsigned)gc < (unsigned)Wdim) hv[0] = rowp[gc];
                            if ((unsigned)(gc + 1) < (unsigned)Wdim) hv[1] = rowp[gc + 1];
                        }
                    }
                }
                kv[p] = hv;
            }
        }
        // r/d halo-2 regs (20x36 = 720 slots)
#pragma unroll
        for (int p = 0; p < 3; ++p) {
            int e = p * 256 + tid;
            int a = e / 36, ee = e - a * 36;
            int gr = r0 - 2 + a, gc = c0 - 2 + ee;
            bool v = (e < 720) && ((unsigned)gr < (unsigned)Hdim) && ((unsigned)gc < (unsigned)Wdim);
            size_t gg = (size_t)gr * Wdim + gc;
            rv1[p] = v ? rb[gg] : 0.f;
            dv1[p] = (v && !isFirst) ? db[gg] : 0.f;
        }
        if (!KH) {
            // fallback: fp32 f load + on-the-fly normalize (unused when ws fits)
            const float* fb = f + (size_t)b * 9 * HW;
            for (int e = tid; e < 18 * 36; e += 256) {
                int sa = e / 36, se = e - sa * 36;
                int gr = r0 - 1 + sa, gc = c0 - 2 + se;
                bool v = ((unsigned)gr < (unsigned)Hdim) && ((unsigned)gc < (unsigned)Wdim);
                size_t gg = (size_t)gr * Wdim + gc;
                float fv[9]; float sab = 0.f;
#pragma unroll
                for (int c = 0; c < 9; ++c) {
                    fv[c] = v ? fb[(size_t)c * HW + gg] : 0.f;
                    sab += fabsf(fv[c]);
                }
                float rd = 1.f / fmaxf(sab, EPSF);
#pragma unroll
                for (int c = 0; c < 9; ++c)
                    sm.z1.kern[c][sa][se] = (_Float16)(fv[c] * rd);
            }
        }
    }

    // ---- beta reduce (identical order in every block) ----
    float s0r = rrp[b * NPB + tid] + ((tid < 32) ? rrp[b * NPB + 256 + tid] : 0.f);
    float delta = blockSum(s0r, red4);
    float beta = isFirst ? 0.f : delta / deltaO[b];
    if (bxg == 0 && tid == 0) {
        deltaN[b] = delta;
        if (isFirst) {
            float th = TOLF * delta;
            thrS[b] = th;
            convN[b] = (delta <= th) ? 1 : 0;
        } else {
            convN[b] = (convO[b] || delta <= thrS[b]) ? 1 : 0;
        }
    }

    if (roleK) {
        // ---- z0: ds = d_new over tile+halo6 ----
#pragma unroll
        for (int p = 0; p < 8; ++p) {
            int e = p * 256 + tid;
            if (e < Z0SLOTS) {
                int a = e / DSW, ee = e - a * DSW;
                sm.z0.ds[a][ee] = isFirst ? rv0[p] : rv0[p] + beta * dv0[p];
            }
        }
        __syncthreads();

        int trr = tid >> 3, tcc = (tid & 7) << 2;
        size_t ooff = bHW + (size_t)(r0 + trr) * Wdim + c0 + tcc;
        float4 dn4 = make_float4(sm.z0.ds[trr + 6][tcc + 6], sm.z0.ds[trr + 6][tcc + 7],
                                 sm.z0.ds[trr + 6][tcc + 8], sm.z0.ds[trr + 6][tcc + 9]);
        *(float4*)(dnew + ooff) = dn4;

        bool interior = (r0 >= 32 && r0 <= 320 && c0 >= 32 && c0 <= 320);

        // ---- t1 = sym_conv(d) over tile+halo4 ----
        if (interior) {
            for (int e = tid; e < 400; e += 256) {
                int lr = e / 10, lc4 = (e - lr * 10) * 4;
                float a0 = 0, a1 = 0, a2 = 0, a3 = 0;
#pragma unroll
                for (int u = 0; u < 5; ++u) {
                    const float* drow = &sm.z0.ds[lr + 4 - u][lc4];
                    float w[8];
#pragma unroll
                    for (int z = 0; z < 8; ++z) w[z] = drow[z];
#pragma unroll
                    for (int v = 0; v < 5; ++v) {
                        float kv2 = krs[u * 5 + v];
                        a0 += kv2 * w[4 - v]; a1 += kv2 * w[5 - v];
                        a2 += kv2 * w[6 - v]; a3 += kv2 * w[7 - v];
                    }
                }
                sm.z0.t1s[lr][lc4] = a0; sm.z0.t1s[lr][lc4 + 1] = a1;
                sm.z0.t1s[lr][lc4 + 2] = a2; sm.z0.t1s[lr][lc4 + 3] = a3;
            }
        } else {
            for (int e = tid; e < T1H * T1W; e += 256) {
                int lr = e / T1W, lc = e - lr * T1W;
                int gi = r0 - 4 + lr, gj = c0 - 4 + lc;
                float v = 0.f;
                if ((unsigned)gi < (unsigned)Hdim && (unsigned)gj < (unsigned)Wdim) {
                    float acc = 0.f;
#pragma unroll
                    for (int u = 0; u < 5; ++u) {
                        int rr = symidx(gi + 2 - u, Hdim) - (r0 - 6);
#pragma unroll
                        for (int vv = 0; vv < 5; ++vv) {
                            int cc = symidx(gj + 2 - vv, Wdim) - (c0 - 6);
                            acc += krs[u * 5 + vv] * sm.z0.ds[rr][cc];
                        }
                    }
                    v = acc;
                }
                sm.z0.t1s[lr][lc] = v;
            }
        }
        __syncthreads();

        // ---- qa = sym_conv_T(t1) ; dq_a partial ----
        int m = r0 + trr, n = c0 + tcc;
        float q0, q1, q2, q3;
        if (interior) {
            float a0 = 0, a1 = 0, a2 = 0, a3 = 0;
#pragma unroll
            for (int u = 0; u < 5; ++u) {
                const float* t1row = &sm.z0.t1s[trr + 2 + u][tcc + 2];
                float w[8];
#pragma unroll
                for (int z = 0; z < 8; ++z) w[z] = t1row[z];
#pragma unroll
                for (int v = 0; v < 5; ++v) {
                    float kv2 = krs[u * 5 + v];
                    a0 += kv2 * w[v]; a1 += kv2 * w[v + 1];
                    a2 += kv2 * w[v + 2]; a3 += kv2 * w[v + 3];
                }
            }
            q0 = a0; q1 = a1; q2 = a2; q3 = a3;
        } else {
            float qo[4];
#pragma unroll
            for (int o = 0; o < 4; ++o) {
                int nn = n + o;
                int pr[2]; int nr = 0;
                pr[nr++] = m + 2;
                if (m < 2)         pr[nr++] = 1 - m;
                if (m >= Hdim - 2) pr[nr++] = 2 * Hdim + 1 - m;
                int pc[2]; int nc = 0;
                pc[nc++] = nn + 2;
                if (nn < 2)         pc[nc++] = 1 - nn;
                if (nn >= Wdim - 2) pc[nc++] = 2 * Wdim + 1 - nn;
                float acc = 0.f;
                for (int a = 0; a < nr; ++a) {
                    int p = pr[a];
                    for (int bb = 0; bb < nc; ++bb) {
                        int qq2 = pc[bb];
#pragma unroll
                        for (int u = 0; u < 5; ++u) {
                            int rr = p + u - 4;
                            if ((unsigned)rr < (unsigned)Hdim) {
                                int lrr = rr - (r0 - 4);
#pragma unroll
                                for (int v = 0; v < 5; ++v) {
                                    int cc = qq2 + v - 4;
                                    if ((unsigned)cc < (unsigned)Wdim)
                                        acc += krs[u * 5 + v] * sm.z0.t1s[lrr][cc - (c0 - 4)];
                                }
                            }
                        }
                    }
                }
                qo[o] = acc;
            }
            q0 = qo[0]; q1 = qo[1]; q2 = qo[2]; q3 = qo[3];
        }
        *(float4*)(qa + ooff) = make_float4(q0, q1, q2, q3);

        float pdq = dn4.x * q0 + dn4.y * q1 + dn4.z * q2 + dn4.w * q3;
        float dq = blockSum(pdq, red4);
        if (tid == 0) dqa[b * NZ0 + bxg] = dq;

    } else {
        int bxl = bxg - NZ0;
        // ---- kern LDS fill from preloaded regs + dsm = d_new over tile+halo2 ----
        if (KH) {
#pragma unroll
            for (int p = 0; p < 12; ++p) {
                int e = p * 256 + tid;
                if (e < KSL) {
                    int cpl = e / 324;
                    int s2 = e - cpl * 324;
                    int sa = s2 / 18, j = s2 - sa * 18;
                    *(h2*)&sm.z1.kern[cpl][sa][2 * j] = kv[p];
                }
            }
        }
#pragma unroll
        for (int p = 0; p < 3; ++p) {
            int e = p * 256 + tid;
            if (e < 720) {
                int a = e / 36, ee = e - a * 36;
                sm.z1.dsm[a][ee] = isFirst ? rv1[p] : rv1[p] + beta * dv1[p];
            }
        }
        __syncthreads();

        // ---- u2[s] = sum_c kern[c,s] * d(s+delta_c)  over 18x34 (se 1..34) ----
        for (int e = tid; e < 612; e += 256) {
            int sa = e / 34, se = 1 + (e - sa * 34);
            float acc = 0.f;
#pragma unroll
            for (int c = 0; c < 9; ++c)
                acc += (float)sm.z1.kern[c][sa][se] * sm.z1.dsm[sa + c / 3][se - 1 + c % 3];
            sm.z1.u2[sa][se] = acc;
        }
        __syncthreads();

        // ---- gather: qb(p) = sum_c kern[c, p-dc] * u2(p-dc) ; dq_b partial ----
        int ti = tid >> 4, tj0 = (tid & 15) << 1;
        h2 qh;
        float pdq = 0.f;
#pragma unroll
        for (int oo = 0; oo < 2; ++oo) {
            int tj = tj0 + oo;
            float qv = 0.f;
#pragma unroll
            for (int c = 0; c < 9; ++c) {
                int sa = ti + 2 - c / 3, se = tj + 3 - c % 3;
                qv += (float)sm.z1.kern[c][sa][se] * sm.z1.u2[sa][se];
            }
            qh[oo] = (_Float16)qv;
            pdq += sm.z1.dsm[ti + 2][tj + 2] * (float)qh[oo];
        }
        *(h2*)(qb + bHW + (size_t)(r0 + ti) * Wdim + c0 + tj0) = qh;
        float dq = blockSum(pdq, red4);
        if (tid == 0) dqb[b * NZ1 + bxl] = dq;
    }
}

// ---------- K2: alpha ; q=qa+lam*qb ; x += a d ; r -= a q ; rr partials ----------

__global__ __launch_bounds__(256) void K2(
    const float* __restrict__ dqa, const float* __restrict__ dqb, const float* __restrict__ rw,
    const float* __restrict__ deltaN, const int* __restrict__ convN,
    const float* __restrict__ d, const float* __restrict__ qa, const _Float16* __restrict__ qb,
    float* __restrict__ x, float* __restrict__ r, float* __restrict__ rrp)
{
    __shared__ float red[512];
    int id = blockIdx.x;
    int b = id & 7, bx = id >> 3, tid = threadIdx.x;
    float sA = (tid < NZ0) ? dqa[b * NZ0 + tid] : 0.f;
    float sB = dqb[b * NZ1 + tid] + ((tid < 32) ? dqb[b * NZ1 + 256 + tid] : 0.f);
    red[tid] = sA; red[256 + tid] = sB;
    __syncthreads();
    for (int st = 128; st > 0; st >>= 1) {
        if (tid < st) { red[tid] += red[tid + st]; red[256 + tid] += red[256 + tid + st]; }
        __syncthreads();
    }
    float lam = expf(rw[0]);
    float dq = red[0] + lam * red[256];
    float a = convN[b] ? 0.f : deltaN[b] / dq;
    __syncthreads();

    size_t off = (size_t)b * HW + ((size_t)bx * 256 + tid) * 2;
    float2 d2  = *(const float2*)(d + off);
    float2 qa2 = *(const float2*)(qa + off);
    h2 qh = *(const h2*)(qb + off);
    float2 xv  = *(float2*)(x + off);
    float2 rv  = *(float2*)(r + off);
    float q0 = qa2.x + lam * (float)qh[0], q1 = qa2.y + lam * (float)qh[1];
    xv.x += a * d2.x; xv.y += a * d2.y;
    rv.x -= a * q0;   rv.y -= a * q1;
    *(float2*)(x + off) = xv;
    *(float2*)(r + off) = rv;

    float ps = rv.x * rv.x + rv.y * rv.y;
    red[tid] = ps; __syncthreads();
    for (int st = 128; st > 0; st >>= 1) {
        if (tid < st) red[tid] += red[tid + st];
        __syncthreads();
    }
    if (tid == 0) rrp[b * NPB + bx] = red[0];
}

// ---------- launch ----------

extern "C" void kernel_launch(void* const* d_in, const int* in_sizes, int n_in,
                              void* d_out, int out_size, void* d_ws, size_t ws_size,
                              hipStream_t stream) {
    const float* y  = (const float*)d_in[0];   // [8,1,384,384]
    const float* kk = (const float*)d_in[1];   // [8,5,5]
    const float* f  = (const float*)d_in[2];   // [8,9,384,384]
    const float* rw = (const float*)d_in[3];   // [1]

    float* x = (float*)d_out;
    float* ws = (float*)d_ws;
    const size_t N = (size_t)Bn * HW;

    float* r    = ws;
    float* d0   = ws + 1 * N;
    float* d1   = ws + 2 * N;
    float* qa   = ws + 3 * N;
    float* qbF  = ws + 4 * N;          // fp16 qb lives in this N-float region
    float* P    = ws + 5 * N;
    float* dqa  = P;                   P += (size_t)Bn * NZ0;
    float* dqb  = P;                   P += (size_t)Bn * NZ1;
    float* rrp  = P;                   P += (size_t)Bn * NPB;
    float* delta = P;                  P += 2 * Bn;
    float* thr   = P;                  P += Bn;
    int*   conv  = (int*)P;            P += 2 * Bn;
    _Float16* kern = (_Float16*)P;     // 9N halves
    _Float16* qb = (_Float16*)qbF;
    size_t needBytes = ((size_t)(P - ws)) * 4 + 9 * N * 2;
    int useH = (ws_size >= needBytes) ? 1 : 0;
    float* db[2] = { d0, d1 };

    dim3 blk(256);

    k_init<<<dim3(NPB, Bn), blk, 0, stream>>>(y, kk, r, x, rrp);
    if (useH) k_prep<<<dim3(NPB * Bn), blk, 0, stream>>>(f, kern);

    for (int t = 0; t < MAXITER; ++t) {
        int i = t & 1, o = i ^ 1;
        if (useH) {
            K1<1><<<dim3((NZ0 + NZ1) * Bn), blk, 0, stream>>>(
                r, db[i], db[o], qa, qb, f, kern, kk,
                rrp, dqa, dqb,
                delta + i * Bn, delta + o * Bn,
                conv + i * Bn, conv + o * Bn,
                thr, t == 0 ? 1 : 0);
        } else {
            K1<0><<<dim3((NZ0 + NZ1) * Bn), blk, 0, stream>>>(
                r, db[i], db[o], qa, qb, f, kern, kk,
                rrp, dqa, dqb,
                delta + i * Bn, delta + o * Bn,
                conv + i * Bn, conv + o * Bn,
                thr, t == 0 ? 1 : 0);
        }
        K2<<<dim3(NPB * Bn), blk, 0, stream>>>(
            dqa, dqb, rw, delta + o * Bn, conv + o * Bn,
            db[o], qa, qb, x, r, rrp);
    }
}

// Round 15
// 1642.069 us; speedup vs baseline: 1.4558x; 1.1381x over previous
//
#include <hip/hip_runtime.h>
#include <math.h>

#define Hdim 384
#define Wdim 384
#define HW (Hdim * Wdim)          // 147456
#define Bn 8
#define MAXITER 50
#define TOLF 1e-6f
#define EPSF 1e-12f

#define NPB 288                   // rr-partial width per image (k_init, K2)
#define NZ0 144                   // z0 (KtK) blocks per image: 12x12 tiles of 32x32
#define NZ1 288                   // z1 (LtL) blocks per image: 24x12 tiles of 16x32

// z0 LDS geometry (32x32 tile, halo 6 / t1 halo 4) — odd strides = natural bank swizzle
#define DSH 44
#define DSW 44
#define DSP 45
#define Z0SLOTS 1936
#define T1H 40
#define T1W 40
#define T1P 41

#define KSL 2916                  // 9 planes * 18 rows * 18 h2-cols

typedef _Float16 h2 __attribute__((ext_vector_type(2)));

struct Z0S { float ds[DSH][DSP]; float t1s[T1H][T1P]; };              // 14480 B
struct Z1S { _Float16 kern[9][18][36]; float dsm[20][37]; float u2[18][36]; }; // 17216 B
union SMemU { Z0S z0; Z1S z1; };

// ---------- helpers ----------

__device__ __forceinline__ int symidx(int t, int n) {
    if (t < 0) t = -t - 1;
    else if (t >= n) t = 2 * n - 1 - t;
    return t;
}

__device__ __forceinline__ float blockReduceSum256(float v) {
    __shared__ float sm[256];
    sm[threadIdx.x] = v;
    __syncthreads();
    for (int s = 128; s > 0; s >>= 1) {
        if (threadIdx.x < s) sm[threadIdx.x] += sm[threadIdx.x + s];
        __syncthreads();
    }
    float r = sm[0];
    __syncthreads();
    return r;
}

// wave-shuffle block sum: identical fixed order in every block (validated r8-r14)
__device__ __forceinline__ float blockSum(float v, float* red4) {
#pragma unroll
    for (int o = 32; o > 0; o >>= 1) v += __shfl_down(v, o, 64);
    int lane = threadIdx.x & 63, wid = threadIdx.x >> 6;
    if (lane == 0) red4[wid] = v;
    __syncthreads();
    float s = (red4[0] + red4[1]) + (red4[2] + red4[3]);
    __syncthreads();
    return s;
}

// global-memory sym_conv_T (k_init only; proven rounds 1-14)
__device__ float symconvT_s(const float* __restrict__ g, const float* kr, int m, int n) {
    int pr[2]; int nr = 0;
    pr[nr++] = m + 2;
    if (m < 2)         pr[nr++] = 1 - m;
    if (m >= Hdim - 2) pr[nr++] = 2 * Hdim + 1 - m;
    int pc[2]; int nc = 0;
    pc[nc++] = n + 2;
    if (n < 2)         pc[nc++] = 1 - n;
    if (n >= Wdim - 2) pc[nc++] = 2 * Wdim + 1 - n;

    float acc = 0.f;
    for (int a = 0; a < nr; ++a) {
        int p = pr[a];
        for (int bb = 0; bb < nc; ++bb) {
            int q = pc[bb];
#pragma unroll
            for (int u = 0; u < 5; ++u) {
                int rr = p + u - 4;
                if ((unsigned)rr < (unsigned)Hdim) {
                    const float* row = g + rr * Wdim;
#pragma unroll
                    for (int v = 0; v < 5; ++v) {
                        int cc = q + v - 4;
                        if ((unsigned)cc < (unsigned)Wdim)
                            acc += kr[u * 5 + v] * row[cc];
                    }
                }
            }
        }
    }
    return acc;
}

// r = b = K^T y ; x = 0 ; partials of b*b
__global__ __launch_bounds__(256) void k_init(const float* __restrict__ y, const float* __restrict__ kk,
                                              float* __restrict__ r, float* __restrict__ x,
                                              float* __restrict__ part) {
    __shared__ float krs[25];
    int b = blockIdx.y;
    if (threadIdx.x < 25) krs[threadIdx.x] = kk[b * 25 + threadIdx.x];
    __syncthreads();
    int p2 = (blockIdx.x * 256 + threadIdx.x) * 2;
    int m = p2 / Wdim, n = p2 - m * Wdim;
    const float* gb = y + (size_t)b * HW;
    float a0 = symconvT_s(gb, krs, m, n);
    float a1 = symconvT_s(gb, krs, m, n + 1);
    size_t off = (size_t)b * HW + p2;
    r[off] = a0; r[off + 1] = a1;
    x[off] = 0.f; x[off + 1] = 0.f;
    float ps = blockReduceSum256(a0 * a0 + a1 * a1);
    if (threadIdx.x == 0) part[b * NPB + blockIdx.x] = ps;
}

// kern = fp16( f * (1/max(sum|f|,eps)) )
__global__ __launch_bounds__(256) void k_prep(const float* __restrict__ f, _Float16* __restrict__ kh) {
    int id = blockIdx.x;
    int b = id & 7;
    int base = (id >> 3) * 512 + threadIdx.x * 2;
    const float* fb = f + (size_t)b * 9 * HW;
    _Float16* khb = kh + (size_t)b * 9 * HW;
    float v0[9], v1[9];
    float s0 = 0.f, s1 = 0.f;
#pragma unroll
    for (int c = 0; c < 9; ++c) {
        float2 fv = *(const float2*)(fb + (size_t)c * HW + base);
        v0[c] = fv.x; v1[c] = fv.y;
        s0 += fabsf(fv.x); s1 += fabsf(fv.y);
    }
    float r0 = 1.f / fmaxf(s0, EPSF);
    float r1 = 1.f / fmaxf(s1, EPSF);
#pragma unroll
    for (int c = 0; c < 9; ++c) {
        khb[(size_t)c * HW + base]     = (_Float16)(v0[c] * r0);
        khb[(size_t)c * HW + base + 1] = (_Float16)(v1[c] * r1);
    }
}

// ---------- K1: role-split (z0: beta/d-build + K^TK ; z1: L^TL gather) ----------

template <int KH>
__global__ __launch_bounds__(256, 4) void K1(
    const float* __restrict__ r, const float* __restrict__ dold, float* __restrict__ dnew,
    float* __restrict__ qa, _Float16* __restrict__ qb,
    const float* __restrict__ f, const _Float16* __restrict__ kern,
    const float* __restrict__ kk,
    const float* __restrict__ rrp, float* __restrict__ dqa, float* __restrict__ dqb,
    const float* __restrict__ deltaO, float* __restrict__ deltaN,
    const int* __restrict__ convO, int* __restrict__ convN,
    float* __restrict__ thrS, int isFirst)
{
    __shared__ SMemU sm;
    __shared__ float red4[4];
    __shared__ float krs[25];

    int id = blockIdx.x;
    int b = id & 7;
    int bxg = id >> 3;
    int tid = threadIdx.x;
    bool roleK = (bxg < NZ0);
    size_t bHW = (size_t)b * HW;
    const float* rb = r + bHW;
    const float* db = dold + bHW;

    // ---- preload (all independent loads issued before the beta reduce) ----
    float rv0[8], dv0[8];
    float rv1[3], dv1[3];
    h2 kv[12];
    int r0, c0;
    if (roleK) {
        int ty = bxg / 12, tx = bxg - ty * 12;
        r0 = ty * 32; c0 = tx * 32;
        if (tid < 25) krs[tid] = kk[b * 25 + tid];
#pragma unroll
        for (int p = 0; p < 8; ++p) {
            int e = p * 256 + tid;
            int a = e / DSW, ee = e - a * DSW;
            int gr = r0 - 6 + a, gc = c0 - 6 + ee;
            bool v = (e < Z0SLOTS) && ((unsigned)gr < (unsigned)Hdim) && ((unsigned)gc < (unsigned)Wdim);
            size_t gg = (size_t)gr * Wdim + gc;
            rv0[p] = v ? rb[gg] : 0.f;
            dv0[p] = (v && !isFirst) ? db[gg] : 0.f;
        }
    } else {
        int bxl = bxg - NZ0;
        int ty = bxl / 12, tx = bxl - ty * 12;
        r0 = ty * 16; c0 = tx * 32;
        if (KH) {
            // fixed-unroll kern preload: 12 independent predicated h2 loads
            const _Float16* khb = kern + (size_t)b * 9 * HW;
#pragma unroll
            for (int p = 0; p < 12; ++p) {
                int e = p * 256 + tid;
                h2 hv; hv[0] = (_Float16)0.f; hv[1] = (_Float16)0.f;
                if (e < KSL) {
                    int cpl = e / 324;
                    int s2 = e - cpl * 324;
                    int sa = s2 / 18, j = s2 - sa * 18;
                    int gr = r0 - 1 + sa, gc = c0 - 2 + 2 * j;
                    if ((unsigned)gr < (unsigned)Hdim) {
                        const _Float16* rowp = khb + (size_t)cpl * HW + (size_t)gr * Wdim;
                        if (gc >= 0 && gc + 1 < Wdim) hv = *(const h2*)(rowp + gc);
                        else {
                            if ((unsigned)gc < (unsigned)Wdim) hv[0] = rowp[gc];
                            if ((unsigned)(gc + 1) < (unsigned)Wdim) hv[1] = rowp[gc + 1];
                        }
                    }
                }
                kv[p] = hv;
            }
        }
        // r/d halo-2 regs (20x36 = 720 slots)
#pragma unroll
        for (int p = 0; p < 3; ++p) {
            int e = p * 256 + tid;
            int a = e / 36, ee = e - a * 36;
            int gr = r0 - 2 + a, gc = c0 - 2 + ee;
            bool v = (e < 720) && ((unsigned)gr < (unsigned)Hdim) && ((unsigned)gc < (unsigned)Wdim);
            size_t gg = (size_t)gr * Wdim + gc;
            rv1[p] = v ? rb[gg] : 0.f;
            dv1[p] = (v && !isFirst) ? db[gg] : 0.f;
        }
        if (!KH) {
            // fallback: fp32 f load + on-the-fly normalize (unused when ws fits)
            const float* fb = f + (size_t)b * 9 * HW;
            for (int e = tid; e < 18 * 36; e += 256) {
                int sa = e / 36, se = e - sa * 36;
                int gr = r0 - 1 + sa, gc = c0 - 2 + se;
                bool v = ((unsigned)gr < (unsigned)Hdim) && ((unsigned)gc < (unsigned)Wdim);
                size_t gg = (size_t)gr * Wdim + gc;
                float fv[9]; float sab = 0.f;
#pragma unroll
                for (int c = 0; c < 9; ++c) {
                    fv[c] = v ? fb[(size_t)c * HW + gg] : 0.f;
                    sab += fabsf(fv[c]);
                }
                float rd = 1.f / fmaxf(sab, EPSF);
#pragma unroll
                for (int c = 0; c < 9; ++c)
                    sm.z1.kern[c][sa][se] = (_Float16)(fv[c] * rd);
            }
        }
    }

    // ---- beta reduce (identical order in every block) ----
    float s0r = rrp[b * NPB + tid] + ((tid < 32) ? rrp[b * NPB + 256 + tid] : 0.f);
    float delta = blockSum(s0r, red4);
    float beta = isFirst ? 0.f : delta / deltaO[b];
    if (bxg == 0 && tid == 0) {
        deltaN[b] = delta;
        if (isFirst) {
            float th = TOLF * delta;
            thrS[b] = th;
            convN[b] = (delta <= th) ? 1 : 0;
        } else {
            convN[b] = (convO[b] || delta <= thrS[b]) ? 1 : 0;
        }
    }

    // Converged image: x frozen forever (alpha forced 0 hereafter in the
    // reference); d/q/r evolution can never affect output -> skip all tile
    // work. Block-uniform branch; scalars above already written.
    if (!isFirst && convO[b]) return;

    if (roleK) {
        // ---- z0: ds = d_new over tile+halo6 ----
#pragma unroll
        for (int p = 0; p < 8; ++p) {
            int e = p * 256 + tid;
            if (e < Z0SLOTS) {
                int a = e / DSW, ee = e - a * DSW;
                sm.z0.ds[a][ee] = isFirst ? rv0[p] : rv0[p] + beta * dv0[p];
            }
        }
        __syncthreads();

        int trr = tid >> 3, tcc = (tid & 7) << 2;
        size_t ooff = bHW + (size_t)(r0 + trr) * Wdim + c0 + tcc;
        float4 dn4 = make_float4(sm.z0.ds[trr + 6][tcc + 6], sm.z0.ds[trr + 6][tcc + 7],
                                 sm.z0.ds[trr + 6][tcc + 8], sm.z0.ds[trr + 6][tcc + 9]);
        *(float4*)(dnew + ooff) = dn4;

        bool interior = (r0 >= 32 && r0 <= 320 && c0 >= 32 && c0 <= 320);

        // ---- t1 = sym_conv(d) over tile+halo4 ----
        if (interior) {
            for (int e = tid; e < 400; e += 256) {
                int lr = e / 10, lc4 = (e - lr * 10) * 4;
                float a0 = 0, a1 = 0, a2 = 0, a3 = 0;
#pragma unroll
                for (int u = 0; u < 5; ++u) {
                    const float* drow = &sm.z0.ds[lr + 4 - u][lc4];
                    float w[8];
#pragma unroll
                    for (int z = 0; z < 8; ++z) w[z] = drow[z];
#pragma unroll
                    for (int v = 0; v < 5; ++v) {
                        float kv2 = krs[u * 5 + v];
                        a0 += kv2 * w[4 - v]; a1 += kv2 * w[5 - v];
                        a2 += kv2 * w[6 - v]; a3 += kv2 * w[7 - v];
                    }
                }
                sm.z0.t1s[lr][lc4] = a0; sm.z0.t1s[lr][lc4 + 1] = a1;
                sm.z0.t1s[lr][lc4 + 2] = a2; sm.z0.t1s[lr][lc4 + 3] = a3;
            }
        } else {
            for (int e = tid; e < T1H * T1W; e += 256) {
                int lr = e / T1W, lc = e - lr * T1W;
                int gi = r0 - 4 + lr, gj = c0 - 4 + lc;
                float v = 0.f;
                if ((unsigned)gi < (unsigned)Hdim && (unsigned)gj < (unsigned)Wdim) {
                    float acc = 0.f;
#pragma unroll
                    for (int u = 0; u < 5; ++u) {
                        int rr = symidx(gi + 2 - u, Hdim) - (r0 - 6);
#pragma unroll
                        for (int vv = 0; vv < 5; ++vv) {
                            int cc = symidx(gj + 2 - vv, Wdim) - (c0 - 6);
                            acc += krs[u * 5 + vv] * sm.z0.ds[rr][cc];
                        }
                    }
                    v = acc;
                }
                sm.z0.t1s[lr][lc] = v;
            }
        }
        __syncthreads();

        // ---- qa = sym_conv_T(t1) ; dq_a partial ----
        int m = r0 + trr, n = c0 + tcc;
        float q0, q1, q2, q3;
        if (interior) {
            float a0 = 0, a1 = 0, a2 = 0, a3 = 0;
#pragma unroll
            for (int u = 0; u < 5; ++u) {
                const float* t1row = &sm.z0.t1s[trr + 2 + u][tcc + 2];
                float w[8];
#pragma unroll
                for (int z = 0; z < 8; ++z) w[z] = t1row[z];
#pragma unroll
                for (int v = 0; v < 5; ++v) {
                    float kv2 = krs[u * 5 + v];
                    a0 += kv2 * w[v]; a1 += kv2 * w[v + 1];
                    a2 += kv2 * w[v + 2]; a3 += kv2 * w[v + 3];
                }
            }
            q0 = a0; q1 = a1; q2 = a2; q3 = a3;
        } else {
            float qo[4];
#pragma unroll
            for (int o = 0; o < 4; ++o) {
                int nn = n + o;
                int pr[2]; int nr = 0;
                pr[nr++] = m + 2;
                if (m < 2)         pr[nr++] = 1 - m;
                if (m >= Hdim - 2) pr[nr++] = 2 * Hdim + 1 - m;
                int pc[2]; int nc = 0;
                pc[nc++] = nn + 2;
                if (nn < 2)         pc[nc++] = 1 - nn;
                if (nn >= Wdim - 2) pc[nc++] = 2 * Wdim + 1 - nn;
                float acc = 0.f;
                for (int a = 0; a < nr; ++a) {
                    int p = pr[a];
                    for (int bb = 0; bb < nc; ++bb) {
                        int qq2 = pc[bb];
#pragma unroll
                        for (int u = 0; u < 5; ++u) {
                            int rr = p + u - 4;
                            if ((unsigned)rr < (unsigned)Hdim) {
                                int lrr = rr - (r0 - 4);
#pragma unroll
                                for (int v = 0; v < 5; ++v) {
                                    int cc = qq2 + v - 4;
                                    if ((unsigned)cc < (unsigned)Wdim)
                                        acc += krs[u * 5 + v] * sm.z0.t1s[lrr][cc - (c0 - 4)];
                                }
                            }
                        }
                    }
                }
                qo[o] = acc;
            }
            q0 = qo[0]; q1 = qo[1]; q2 = qo[2]; q3 = qo[3];
        }
        *(float4*)(qa + ooff) = make_float4(q0, q1, q2, q3);

        float pdq = dn4.x * q0 + dn4.y * q1 + dn4.z * q2 + dn4.w * q3;
        float dq = blockSum(pdq, red4);
        if (tid == 0) dqa[b * NZ0 + bxg] = dq;

    } else {
        int bxl = bxg - NZ0;
        // ---- kern LDS fill from preloaded regs + dsm = d_new over tile+halo2 ----
        if (KH) {
#pragma unroll
            for (int p = 0; p < 12; ++p) {
                int e = p * 256 + tid;
                if (e < KSL) {
                    int cpl = e / 324;
                    int s2 = e - cpl * 324;
                    int sa = s2 / 18, j = s2 - sa * 18;
                    *(h2*)&sm.z1.kern[cpl][sa][2 * j] = kv[p];
                }
            }
        }
#pragma unroll
        for (int p = 0; p < 3; ++p) {
            int e = p * 256 + tid;
            if (e < 720) {
                int a = e / 36, ee = e - a * 36;
                sm.z1.dsm[a][ee] = isFirst ? rv1[p] : rv1[p] + beta * dv1[p];
            }
        }
        __syncthreads();

        // ---- u2[s] = sum_c kern[c,s] * d(s+delta_c)  over 18x34 (se 1..34) ----
        for (int e = tid; e < 612; e += 256) {
            int sa = e / 34, se = 1 + (e - sa * 34);
            float acc = 0.f;
#pragma unroll
            for (int c = 0; c < 9; ++c)
                acc += (float)sm.z1.kern[c][sa][se] * sm.z1.dsm[sa + c / 3][se - 1 + c % 3];
            sm.z1.u2[sa][se] = acc;
        }
        __syncthreads();

        // ---- gather: qb(p) = sum_c kern[c, p-dc] * u2(p-dc) ; dq_b partial ----
        int ti = tid >> 4, tj0 = (tid & 15) << 1;
        h2 qh;
        float pdq = 0.f;
#pragma unroll
        for (int oo = 0; oo < 2; ++oo) {
            int tj = tj0 + oo;
            float qv = 0.f;
#pragma unroll
            for (int c = 0; c < 9; ++c) {
                int sa = ti + 2 - c / 3, se = tj + 3 - c % 3;
                qv += (float)sm.z1.kern[c][sa][se] * sm.z1.u2[sa][se];
            }
            qh[oo] = (_Float16)qv;
            pdq += sm.z1.dsm[ti + 2][tj + 2] * (float)qh[oo];
        }
        *(h2*)(qb + bHW + (size_t)(r0 + ti) * Wdim + c0 + tj0) = qh;
        float dq = blockSum(pdq, red4);
        if (tid == 0) dqb[b * NZ1 + bxl] = dq;
    }
}

// ---------- K2: alpha ; q=qa+lam*qb ; x += a d ; r -= a q ; rr partials ----------

__global__ __launch_bounds__(256) void K2(
    const float* __restrict__ dqa, const float* __restrict__ dqb, const float* __restrict__ rw,
    const float* __restrict__ deltaN, const int* __restrict__ convN,
    const float* __restrict__ d, const float* __restrict__ qa, const _Float16* __restrict__ qb,
    float* __restrict__ x, float* __restrict__ r, float* __restrict__ rrp)
{
    __shared__ float red[512];
    int id = blockIdx.x;
    int b = id & 7, bx = id >> 3, tid = threadIdx.x;

    // Converged image: alpha = 0 -> x,r frozen; skip all vector work.
    // (Stale rrp is fine: next K1 early-exits on convO and never uses beta.)
    if (convN[b]) return;

    float sA = (tid < NZ0) ? dqa[b * NZ0 + tid] : 0.f;
    float sB = dqb[b * NZ1 + tid] + ((tid < 32) ? dqb[b * NZ1 + 256 + tid] : 0.f);
    red[tid] = sA; red[256 + tid] = sB;
    __syncthreads();
    for (int st = 128; st > 0; st >>= 1) {
        if (tid < st) { red[tid] += red[tid + st]; red[256 + tid] += red[256 + tid + st]; }
        __syncthreads();
    }
    float lam = expf(rw[0]);
    float dq = red[0] + lam * red[256];
    float a = deltaN[b] / dq;
    __syncthreads();

    size_t off = (size_t)b * HW + ((size_t)bx * 256 + tid) * 2;
    float2 d2  = *(const float2*)(d + off);
    float2 qa2 = *(const float2*)(qa + off);
    h2 qh = *(const h2*)(qb + off);
    float2 xv  = *(float2*)(x + off);
    float2 rv  = *(float2*)(r + off);
    float q0 = qa2.x + lam * (float)qh[0], q1 = qa2.y + lam * (float)qh[1];
    xv.x += a * d2.x; xv.y += a * d2.y;
    rv.x -= a * q0;   rv.y -= a * q1;
    *(float2*)(x + off) = xv;
    *(float2*)(r + off) = rv;

    float ps = rv.x * rv.x + rv.y * rv.y;
    red[tid] = ps; __syncthreads();
    for (int st = 128; st > 0; st >>= 1) {
        if (tid < st) red[tid] += red[tid + st];
        __syncthreads();
    }
    if (tid == 0) rrp[b * NPB + bx] = red[0];
}

// ---------- launch ----------

extern "C" void kernel_launch(void* const* d_in, const int* in_sizes, int n_in,
                              void* d_out, int out_size, void* d_ws, size_t ws_size,
                              hipStream_t stream) {
    const float* y  = (const float*)d_in[0];   // [8,1,384,384]
    const float* kk = (const float*)d_in[1];   // [8,5,5]
    const float* f  = (const float*)d_in[2];   // [8,9,384,384]
    const float* rw = (const float*)d_in[3];   // [1]

    float* x = (float*)d_out;
    float* ws = (float*)d_ws;
    const size_t N = (size_t)Bn * HW;

    float* r    = ws;
    float* d0   = ws + 1 * N;
    float* d1   = ws + 2 * N;
    float* qa   = ws + 3 * N;
    float* qbF  = ws + 4 * N;          // fp16 qb lives in this N-float region
    float* P    = ws + 5 * N;
    float* dqa  = P;                   P += (size_t)Bn * NZ0;
    float* dqb  = P;                   P += (size_t)Bn * NZ1;
    float* rrp  = P;                   P += (size_t)Bn * NPB;
    float* delta = P;                  P += 2 * Bn;
    float* thr   = P;                  P += Bn;
    int*   conv  = (int*)P;            P += 2 * Bn;
    _Float16* kern = (_Float16*)P;     // 9N halves
    _Float16* qb = (_Float16*)qbF;
    size_t needBytes = ((size_t)(P - ws)) * 4 + 9 * N * 2;
    int useH = (ws_size >= needBytes) ? 1 : 0;
    float* db[2] = { d0, d1 };

    dim3 blk(256);

    k_init<<<dim3(NPB, Bn), blk, 0, stream>>>(y, kk, r, x, rrp);
    if (useH) k_prep<<<dim3(NPB * Bn), blk, 0, stream>>>(f, kern);

    for (int t = 0; t < MAXITER; ++t) {
        int i = t & 1, o = i ^ 1;
        if (useH) {
            K1<1><<<dim3((NZ0 + NZ1) * Bn), blk, 0, stream>>>(
                r, db[i], db[o], qa, qb, f, kern, kk,
                rrp, dqa, dqb,
                delta + i * Bn, delta + o * Bn,
                conv + i * Bn, conv + o * Bn,
                thr, t == 0 ? 1 : 0);
        } else {
            K1<0><<<dim3((NZ0 + NZ1) * Bn), blk, 0, stream>>>(
                r, db[i], db[o], qa, qb, f, kern, kk,
                rrp, dqa, dqb,
                delta + i * Bn, delta + o * Bn,
                conv + i * Bn, conv + o * Bn,
                thr, t == 0 ? 1 : 0);
        }
        K2<<<dim3(NPB * Bn), blk, 0, stream>>>(
            dqa, dqb, rw, delta + o * Bn, conv + o * Bn,
            db[o], qa, qb, x, r, rrp);
    }
}